// Round 11
// baseline (64.131 us; speedup 1.0000x reference)
//
#include <hip/hip_runtime.h>
#include <stdint.h>

// Problem dims: B=1, H=W=128, HW=16384, P=128, F=64
#define HW 16384
#define P 128
#define F 64

// Wave-local LDS ordering: producer ds_writes complete before consumer reads.
// No s_barrier — each wave only touches its own LDS region. (rule #18)
#define WAVE_SYNC()                                          \
    do {                                                     \
        asm volatile("s_waitcnt lgkmcnt(0)" ::: "memory");   \
        __builtin_amdgcn_sched_barrier(0);                   \
    } while (0)

// One ray per wave-iteration; 4 waves x 4 serial rays = 16 consecutive rays
// per block. Per-ray pipeline is barrier-free; one __syncthreads at the end
// for the coalesced (full-cache-line) transposed output writes.
__global__ __launch_bounds__(256) void nerf_wave_kernel(
    const float* __restrict__ sigma,     // [HW][P]
    const float* __restrict__ feat,      // [HW][P][F]
    const float* __restrict__ depth,     // [HW][P]
    const float* __restrict__ rays_dir,  // [HW][3]
    float* __restrict__ out_feat,        // [F][HW]
    float* __restrict__ out_depth,       // [HW]
    float* __restrict__ out_alpha,       // [HW]
    float* __restrict__ out_weights)     // [HW][P] (sorted-sample order)
{
    const int tid   = threadIdx.x;
    const int lane  = tid & 63;
    const int wv    = tid >> 6;
    const int rbase = blockIdx.x * 16;

    // per-wave private LDS regions (no cross-wave sharing inside the loop)
    __shared__ float lsdep[4][P];   // sorted depth
    __shared__ float lssig[4][P];   // sorted sigma
    __shared__ int   lplist[4][P];  // compacted nonzero-w original indices
    __shared__ float lswc[4][P];    // compacted weights
    __shared__ float stile[F][17];  // staged feat results (padded: no conflicts)
    __shared__ float sdm[16];       // staged depth_map
    __shared__ float sam[16];       // staged alpha_map
    float* sdep  = lsdep[wv];
    float* ssig  = lssig[wv];
    int*   plist = lplist[wv];
    float* swc   = lswc[wv];

    const int f4   = lane & 15;   // float4 chunk of F
    const int psub = lane >> 4;   // 0..3

    for (int i = 0; i < 4; ++i) {
        const int r   = rbase + wv * 4 + i;
        const int col = wv * 4 + i;

        // ---- loads: 2 samples per lane (coalesced 256 B x2 per wave) ----
        const float d0 = depth[(size_t)r * P + lane];
        const float d1 = depth[(size_t)r * P + 64 + lane];
        const float g0 = sigma[(size_t)r * P + lane];
        const float g1 = sigma[(size_t)r * P + 64 + lane];
        const float rx = rays_dir[r * 3 + 0];
        const float ry = rays_dir[r * 3 + 1];
        const float rz = rays_dir[r * 3 + 2];
        const float rn = sqrtf(rx * rx + ry * ry + rz * rz);

        // ---- stable rank sort (u32 depth bits monotonic for depth in [0,1),
        // exact jnp.argsort stability via original-index tie-break) ----
        const unsigned b0 = __float_as_uint(d0);   // orig index lane
        const unsigned b1 = __float_as_uint(d1);   // orig index 64+lane
        int rank0 = 0, rank1 = 0;
        #pragma unroll 8
        for (int j = 0; j < 64; ++j) {
            const unsigned q0 = (unsigned)__shfl((int)b0, j);   // orig idx j
            const unsigned q1 = (unsigned)__shfl((int)b1, j);   // orig idx 64+j
            rank0 += (q0 < b0 || (q0 == b0 && j < lane)) ? 1 : 0;
            rank0 += (q1 < b0) ? 1 : 0;                  // 64+j > lane: tie loses
            rank1 += (q0 < b1 || q0 == b1) ? 1 : 0;      // j < 64+lane: tie wins
            rank1 += (q1 < b1 || (q1 == b1 && j < lane)) ? 1 : 0;
        }

        // ---- permute depth/sigma to sorted order via per-wave LDS ----
        sdep[rank0] = d0; sdep[rank1] = d1;
        ssig[rank0] = g0; ssig[rank1] = g1;
        WAVE_SYNC();
        const float sd_lo = sdep[lane];        // position lane
        const float sd_hi = sdep[64 + lane];   // position 64+lane
        const float sg_lo = ssig[lane];
        const float sg_hi = ssig[64 + lane];

        // ---- dists: d[q+1] - d[q]; last position gets 1e10 ----
        float dn_lo = __shfl_down(sd_lo, 1);
        const float sd_hi0 = __shfl(sd_hi, 0);
        if (lane == 63) dn_lo = sd_hi0;
        const float dn_hi = __shfl_down(sd_hi, 1);
        const float dz_lo = dn_lo - sd_lo;
        const float dz_hi = (lane == 63) ? 1e10f : (dn_hi - sd_hi);

        // ---- alpha, tp (match ref expression order) ----
        const float a_lo  = 1.0f - expf(-fmaxf(sg_lo, 0.0f) * dz_lo * rn);
        const float a_hi  = 1.0f - expf(-fmaxf(sg_hi, 0.0f) * dz_hi * rn);
        const float tp_lo = (1.0f - a_lo) + 1e-10f;
        const float tp_hi = (1.0f - a_hi) + 1e-10f;

        // ---- inclusive product scan over 128 positions ----
        float sc_lo = tp_lo, sc_hi = tp_hi;
        #pragma unroll
        for (int off = 1; off < 64; off <<= 1) {
            const float vl = __shfl_up(sc_lo, off);
            const float vh = __shfl_up(sc_hi, off);
            if (lane >= off) { sc_lo *= vl; sc_hi *= vh; }
        }
        const float tot_lo = __shfl(sc_lo, 63);
        float tr_lo = __shfl_up(sc_lo, 1);
        float tr_hi = __shfl_up(sc_hi, 1);
        if (lane == 0) { tr_lo = 1.0f; tr_hi = 1.0f; }
        tr_hi *= tot_lo;
        const float w_lo = a_lo * tr_lo;
        const float w_hi = a_hi * tr_hi;

        // ---- weights output (sorted order, contiguous 512 B per ray) ----
        out_weights[(size_t)r * P + lane]      = w_lo;
        out_weights[(size_t)r * P + 64 + lane] = w_hi;

        float s1 = w_lo + w_hi;                    // w >= 0 so |w| = w
        float s2 = w_lo * sd_lo + w_hi * sd_hi;
        #pragma unroll
        for (int off = 32; off > 0; off >>= 1) {
            s1 += __shfl_xor(s1, off);
            s2 += __shfl_xor(s2, off);
        }
        if (lane == 0) {
            float dm = s2 / fmaxf(s1, 1e-12f);
            dm = (dm - 0.001f) / (1000.0f - 0.001f);
            dm = fminf(fmaxf(dm, 0.0f), 1.0f);
            sdm[col] = dm;
            sam[col] = s1;
        }

        // ---- w back to ORIGINAL sample order (pull from rank position) ----
        const float wa0 = __shfl(w_lo, rank0 & 63);
        const float wb0 = __shfl(w_hi, rank0 & 63);
        const float wo0 = (rank0 < 64) ? wa0 : wb0;   // orig sample lane
        const float wa1 = __shfl(w_lo, rank1 & 63);
        const float wb1 = __shfl(w_hi, rank1 & 63);
        const float wo1 = (rank1 < 64) ? wa1 : wb1;   // orig sample 64+lane

        // ---- nonzero compaction (ascending original p) into per-wave LDS ----
        const unsigned long long m0 = __ballot(wo0 != 0.0f);
        const unsigned long long m1 = __ballot(wo1 != 0.0f);
        const int M = (int)(__popcll(m0) + __popcll(m1));
        const unsigned long long lmask = (1ull << lane) - 1ull;  // bits < lane
        if (wo0 != 0.0f) {
            const int pos = (int)__popcll(m0 & lmask);
            plist[pos] = lane; swc[pos] = wo0;
        }
        if (wo1 != 0.0f) {
            const int pos = (int)__popcll(m0) + (int)__popcll(m1 & lmask);
            plist[pos] = 64 + lane; swc[pos] = wo1;
        }
        WAVE_SYNC();

        // ---- feat gather: chunks of 8 independent 1 KB loads ----
        const float4* fp = (const float4*)(feat + (size_t)r * P * F);
        const int jcap = (M > 0) ? (M - 1) : 0;
        const int nch  = (M + 31) >> 5;

        float4 acc = make_float4(0.f, 0.f, 0.f, 0.f);
        for (int c = 0; c < nch; ++c) {
            const int base = c * 32;
            int   pj[8];
            float wj[8];
            #pragma unroll
            for (int q = 0; q < 8; ++q) {
                const int idx = base + q * 4 + psub;
                const int j   = (idx < M) ? idx : jcap;
                pj[q] = plist[j] & (P - 1);
                wj[q] = (idx < M) ? swc[j] : 0.0f;
            }
            float4 fv[8];
            #pragma unroll
            for (int q = 0; q < 8; ++q)
                fv[q] = fp[pj[q] * (F / 4) + f4];
            #pragma unroll
            for (int q = 0; q < 8; ++q) {
                acc.x += wj[q] * fv[q].x;
                acc.y += wj[q] * fv[q].y;
                acc.z += wj[q] * fv[q].z;
                acc.w += wj[q] * fv[q].w;
            }
        }

        // reduce over psub (lane bits 4,5)
        acc.x += __shfl_xor(acc.x, 16); acc.y += __shfl_xor(acc.y, 16);
        acc.z += __shfl_xor(acc.z, 16); acc.w += __shfl_xor(acc.w, 16);
        acc.x += __shfl_xor(acc.x, 32); acc.y += __shfl_xor(acc.y, 32);
        acc.z += __shfl_xor(acc.z, 32); acc.w += __shfl_xor(acc.w, 32);

        if (psub == 0) {   // stage to LDS tile (written coalesced at the end)
            stile[f4 * 4 + 0][col] = acc.x;
            stile[f4 * 4 + 1][col] = acc.y;
            stile[f4 * 4 + 2][col] = acc.z;
            stile[f4 * 4 + 3][col] = acc.w;
        }
    }

    __syncthreads();   // all 16 rays staged; full drain fine (loads consumed)

    // ---- coalesced output: 16 consecutive rays -> full 64 B line segments ----
    const int c  = tid & 15;   // ray offset within block
    const int fr = tid >> 4;   // 0..15 -> features fr*4..fr*4+3
    #pragma unroll
    for (int k = 0; k < 4; ++k)
        out_feat[(size_t)(fr * 4 + k) * HW + rbase + c] = stile[fr * 4 + k][c];
    if (tid < 16)      out_depth[rbase + tid] = sdm[tid];
    else if (tid < 32) out_alpha[rbase + tid - 16] = sam[tid - 16];
}

extern "C" void kernel_launch(void* const* d_in, const int* in_sizes, int n_in,
                              void* d_out, int out_size, void* d_ws, size_t ws_size,
                              hipStream_t stream) {
    const float* sigma    = (const float*)d_in[0];
    const float* feat     = (const float*)d_in[1];
    const float* depth    = (const float*)d_in[2];
    // d_in[3] = semantic: sorted in the reference but unused in every output.
    const float* rays_dir = (const float*)d_in[4];

    float* out = (float*)d_out;
    // Flat output layout (return order): feat_map[64*16384], depth_map[16384],
    // alpha_map[16384], weights[16384*128]
    float* out_feat    = out;
    float* out_depth   = out + (size_t)F * HW;
    float* out_alpha   = out_depth + HW;
    float* out_weights = out_alpha + HW;

    nerf_wave_kernel<<<HW / 16, 256, 0, stream>>>(sigma, feat, depth, rays_dir,
                                                  out_feat, out_depth, out_alpha,
                                                  out_weights);
}

// Round 13
// 62.239 us; speedup vs baseline: 1.0304x; 1.0304x over previous
//
#include <hip/hip_runtime.h>
#include <stdint.h>

// Problem dims: B=1, H=W=128, HW=16384, P=128, F=64
#define HW 16384
#define P 128
#define F 64

// Wave-local LDS ordering: producer ds_writes complete before consumer reads.
// No s_barrier — each wave only touches its own LDS region. (rule #18)
#define WAVE_SYNC()                                          \
    do {                                                     \
        asm volatile("s_waitcnt lgkmcnt(0)" ::: "memory");   \
        __builtin_amdgcn_sched_barrier(0);                   \
    } while (0)

// One ray per WAVE, 4 rays per block, zero __syncthreads.
__global__ __launch_bounds__(256) void nerf_wave_kernel(
    const float* __restrict__ sigma,     // [HW][P]
    const float* __restrict__ feat,      // [HW][P][F]
    const float* __restrict__ depth,     // [HW][P]
    const float* __restrict__ rays_dir,  // [HW][3]
    float* __restrict__ out_feat,        // [F][HW]
    float* __restrict__ out_depth,       // [HW]
    float* __restrict__ out_alpha,       // [HW]
    float* __restrict__ out_weights)     // [HW][P] (sorted-sample order)
{
    const int tid  = threadIdx.x;
    const int lane = tid & 63;
    const int wv   = tid >> 6;
    const int r    = blockIdx.x * 4 + wv;

    // per-wave private LDS regions (no cross-wave sharing -> no barriers)
    __shared__ float lsdep[4][P];   // sorted depth
    __shared__ float lssig[4][P];   // sorted sigma
    __shared__ int   lplist[4][P];  // compacted nonzero-w original indices
    __shared__ float lswc[4][P];    // compacted weights
    float* sdep  = lsdep[wv];
    float* ssig  = lssig[wv];
    int*   plist = lplist[wv];
    float* swc   = lswc[wv];

    // ---- loads: 2 samples per lane (coalesced 256 B x2 per wave) ----
    const float d0 = depth[(size_t)r * P + lane];
    const float d1 = depth[(size_t)r * P + 64 + lane];
    const float g0 = sigma[(size_t)r * P + lane];
    const float g1 = sigma[(size_t)r * P + 64 + lane];
    const float rx = rays_dir[r * 3 + 0];
    const float ry = rays_dir[r * 3 + 1];
    const float rz = rays_dir[r * 3 + 2];
    const float rn = sqrtf(rx * rx + ry * ry + rz * rz);

    // ---- stable rank sort (u32 depth bits monotonic for depth in [0,1),
    // exact jnp.argsort stability via original-index tie-break) ----
    const unsigned b0 = __float_as_uint(d0);   // orig index lane
    const unsigned b1 = __float_as_uint(d1);   // orig index 64+lane
    int rank0 = 0, rank1 = 0;
    #pragma unroll 8
    for (int j = 0; j < 64; ++j) {
        const unsigned q0 = (unsigned)__shfl((int)b0, j);   // orig idx j
        const unsigned q1 = (unsigned)__shfl((int)b1, j);   // orig idx 64+j
        rank0 += (q0 < b0 || (q0 == b0 && j < lane)) ? 1 : 0;
        rank0 += (q1 < b0) ? 1 : 0;                  // 64+j > lane: tie loses
        rank1 += (q0 < b1 || q0 == b1) ? 1 : 0;      // j < 64+lane: tie wins
        rank1 += (q1 < b1 || (q1 == b1 && j < lane)) ? 1 : 0;
    }

    // ---- permute depth/sigma to sorted order via per-wave LDS ----
    sdep[rank0] = d0; sdep[rank1] = d1;
    ssig[rank0] = g0; ssig[rank1] = g1;
    WAVE_SYNC();
    const float sd_lo = sdep[lane];        // position lane
    const float sd_hi = sdep[64 + lane];   // position 64+lane
    const float sg_lo = ssig[lane];
    const float sg_hi = ssig[64 + lane];

    // ---- dists: d[q+1] - d[q]; last position gets 1e10 ----
    float dn_lo = __shfl_down(sd_lo, 1);
    const float sd_hi0 = __shfl(sd_hi, 0);
    if (lane == 63) dn_lo = sd_hi0;
    const float dn_hi = __shfl_down(sd_hi, 1);
    const float dz_lo = dn_lo - sd_lo;
    const float dz_hi = (lane == 63) ? 1e10f : (dn_hi - sd_hi);

    // ---- alpha, tp (match ref expression order) ----
    const float a_lo  = 1.0f - expf(-fmaxf(sg_lo, 0.0f) * dz_lo * rn);
    const float a_hi  = 1.0f - expf(-fmaxf(sg_hi, 0.0f) * dz_hi * rn);
    const float tp_lo = (1.0f - a_lo) + 1e-10f;
    const float tp_hi = (1.0f - a_hi) + 1e-10f;

    // ---- inclusive product scan over 128 positions (lo scan, hi scan, glue) --
    float sc_lo = tp_lo, sc_hi = tp_hi;
    #pragma unroll
    for (int off = 1; off < 64; off <<= 1) {
        const float vl = __shfl_up(sc_lo, off);
        const float vh = __shfl_up(sc_hi, off);
        if (lane >= off) { sc_lo *= vl; sc_hi *= vh; }
    }
    const float tot_lo = __shfl(sc_lo, 63);
    // exclusive transmittance
    float tr_lo = __shfl_up(sc_lo, 1);
    float tr_hi = __shfl_up(sc_hi, 1);
    if (lane == 0) { tr_lo = 1.0f; tr_hi = 1.0f; }
    tr_hi *= tot_lo;
    const float w_lo = a_lo * tr_lo;
    const float w_hi = a_hi * tr_hi;

    // ---- outputs: weights (sorted order), depth_map, alpha_map ----
    out_weights[(size_t)r * P + lane]      = w_lo;
    out_weights[(size_t)r * P + 64 + lane] = w_hi;

    float s1 = w_lo + w_hi;                    // w >= 0 so |w| = w
    float s2 = w_lo * sd_lo + w_hi * sd_hi;
    #pragma unroll
    for (int off = 32; off > 0; off >>= 1) {
        s1 += __shfl_xor(s1, off);
        s2 += __shfl_xor(s2, off);
    }
    if (lane == 0) {
        float dm = s2 / fmaxf(s1, 1e-12f);
        dm = (dm - 0.001f) / (1000.0f - 0.001f);
        dm = fminf(fmaxf(dm, 0.0f), 1.0f);
        out_depth[r] = dm;
        out_alpha[r] = s1;
    }

    // ---- w back to ORIGINAL sample order (pull from rank position) ----
    const float wa0 = __shfl(w_lo, rank0 & 63);
    const float wb0 = __shfl(w_hi, rank0 & 63);
    const float wo0 = (rank0 < 64) ? wa0 : wb0;   // orig sample lane
    const float wa1 = __shfl(w_lo, rank1 & 63);
    const float wb1 = __shfl(w_hi, rank1 & 63);
    const float wo1 = (rank1 < 64) ? wa1 : wb1;   // orig sample 64+lane

    // ---- nonzero compaction (ascending original p) into per-wave LDS ----
    const unsigned long long m0 = __ballot(wo0 != 0.0f);
    const unsigned long long m1 = __ballot(wo1 != 0.0f);
    const int M = (int)(__popcll(m0) + __popcll(m1));
    // bits strictly below `lane`; (1ull << lane) - 1 is well-defined for lane<=63
    const unsigned long long lmask = (1ull << lane) - 1ull;
    if (wo0 != 0.0f) {
        const int pos = (int)__popcll(m0 & lmask);
        plist[pos] = lane; swc[pos] = wo0;
    }
    if (wo1 != 0.0f) {
        const int pos = (int)__popcll(m0) + (int)__popcll(m1 & lmask);
        plist[pos] = 64 + lane; swc[pos] = wo1;
    }
    WAVE_SYNC();

    // ---- feat gather: 16-deep batches (64 rows in flight per wave) ----
    const int f4   = lane & 15;   // float4 chunk of F
    const int psub = lane >> 4;   // 0..3
    const float4* fp = (const float4*)(feat + (size_t)r * P * F);
    const int jcap = (M > 0) ? (M - 1) : 0;

    float4 acc = make_float4(0.f, 0.f, 0.f, 0.f);

    // batch 0: compacted rows 0..63 (always; clamped slots contribute w=0,
    // duplicate clamped loads are L1 hits, not HBM traffic)
    {
        int   pj[16];
        float wj[16];
        #pragma unroll
        for (int i = 0; i < 16; ++i) {
            const int idx = i * 4 + psub;
            const int j   = (idx < M) ? idx : jcap;
            pj[i] = plist[j] & (P - 1);
            wj[i] = (idx < M) ? swc[j] : 0.0f;
        }
        float4 fv[16];
        #pragma unroll
        for (int i = 0; i < 16; ++i)     // 16 independent loads in flight
            fv[i] = fp[pj[i] * (F / 4) + f4];
        #pragma unroll
        for (int i = 0; i < 16; ++i) {
            acc.x += wj[i] * fv[i].x;
            acc.y += wj[i] * fv[i].y;
            acc.z += wj[i] * fv[i].z;
            acc.w += wj[i] * fv[i].w;
        }
    }
    // batch 1: compacted rows 64..127, only when present (~46% of rays;
    // wave-uniform branch — M is uniform across the wave)
    if (M > 64) {
        int   pj[16];
        float wj[16];
        #pragma unroll
        for (int i = 0; i < 16; ++i) {
            const int idx = 64 + i * 4 + psub;
            const int j   = (idx < M) ? idx : jcap;
            pj[i] = plist[j] & (P - 1);
            wj[i] = (idx < M) ? swc[j] : 0.0f;
        }
        float4 fv[16];
        #pragma unroll
        for (int i = 0; i < 16; ++i)
            fv[i] = fp[pj[i] * (F / 4) + f4];
        #pragma unroll
        for (int i = 0; i < 16; ++i) {
            acc.x += wj[i] * fv[i].x;
            acc.y += wj[i] * fv[i].y;
            acc.z += wj[i] * fv[i].z;
            acc.w += wj[i] * fv[i].w;
        }
    }

    // reduce over psub (lane bits 4,5)
    acc.x += __shfl_xor(acc.x, 16); acc.y += __shfl_xor(acc.y, 16);
    acc.z += __shfl_xor(acc.z, 16); acc.w += __shfl_xor(acc.w, 16);
    acc.x += __shfl_xor(acc.x, 32); acc.y += __shfl_xor(acc.y, 32);
    acc.z += __shfl_xor(acc.z, 32); acc.w += __shfl_xor(acc.w, 32);

    if (psub == 0) {
        const int f = f4 * 4;
        out_feat[(size_t)(f + 0) * HW + r] = acc.x;
        out_feat[(size_t)(f + 1) * HW + r] = acc.y;
        out_feat[(size_t)(f + 2) * HW + r] = acc.z;
        out_feat[(size_t)(f + 3) * HW + r] = acc.w;
    }
}

extern "C" void kernel_launch(void* const* d_in, const int* in_sizes, int n_in,
                              void* d_out, int out_size, void* d_ws, size_t ws_size,
                              hipStream_t stream) {
    const float* sigma    = (const float*)d_in[0];
    const float* feat     = (const float*)d_in[1];
    const float* depth    = (const float*)d_in[2];
    // d_in[3] = semantic: sorted in the reference but unused in every output.
    const float* rays_dir = (const float*)d_in[4];

    float* out = (float*)d_out;
    // Flat output layout (return order): feat_map[64*16384], depth_map[16384],
    // alpha_map[16384], weights[16384*128]
    float* out_feat    = out;
    float* out_depth   = out + (size_t)F * HW;
    float* out_alpha   = out_depth + HW;
    float* out_weights = out_alpha + HW;

    nerf_wave_kernel<<<HW / 4, 256, 0, stream>>>(sigma, feat, depth, rays_dir,
                                                 out_feat, out_depth, out_alpha,
                                                 out_weights);
}

// Round 14
// 59.350 us; speedup vs baseline: 1.0806x; 1.0487x over previous
//
#include <hip/hip_runtime.h>
#include <stdint.h>

// Problem dims: B=1, H=W=128, HW=16384, P=128, F=64
#define HW 16384
#define P 128
#define F 64

// Wave-local LDS ordering: producer ds_writes complete before consumer reads.
// No s_barrier — each wave only touches its own LDS region. (rule #18)
#define WAVE_SYNC()                                          \
    do {                                                     \
        asm volatile("s_waitcnt lgkmcnt(0)" ::: "memory");   \
        __builtin_amdgcn_sched_barrier(0);                   \
    } while (0)

// One ray per WAVE, 4 rays per block, zero __syncthreads.
// Best-measured structure (R10: 59.2 us). 8-deep gather chunks keep VGPR
// below the 128 occupancy step (R13's 16-deep variant regressed via
// register pressure).
__global__ __launch_bounds__(256) void nerf_wave_kernel(
    const float* __restrict__ sigma,     // [HW][P]
    const float* __restrict__ feat,      // [HW][P][F]
    const float* __restrict__ depth,     // [HW][P]
    const float* __restrict__ rays_dir,  // [HW][3]
    float* __restrict__ out_feat,        // [F][HW]
    float* __restrict__ out_depth,       // [HW]
    float* __restrict__ out_alpha,       // [HW]
    float* __restrict__ out_weights)     // [HW][P] (sorted-sample order)
{
    const int tid  = threadIdx.x;
    const int lane = tid & 63;
    const int wv   = tid >> 6;
    const int r    = blockIdx.x * 4 + wv;

    // per-wave private LDS regions (no cross-wave sharing -> no barriers)
    __shared__ float lsdep[4][P];   // sorted depth
    __shared__ float lssig[4][P];   // sorted sigma
    __shared__ int   lplist[4][P];  // compacted nonzero-w original indices
    __shared__ float lswc[4][P];    // compacted weights
    float* sdep  = lsdep[wv];
    float* ssig  = lssig[wv];
    int*   plist = lplist[wv];
    float* swc   = lswc[wv];

    // ---- loads: 2 samples per lane (coalesced 256 B x2 per wave) ----
    const float d0 = depth[(size_t)r * P + lane];
    const float d1 = depth[(size_t)r * P + 64 + lane];
    const float g0 = sigma[(size_t)r * P + lane];
    const float g1 = sigma[(size_t)r * P + 64 + lane];
    const float rx = rays_dir[r * 3 + 0];
    const float ry = rays_dir[r * 3 + 1];
    const float rz = rays_dir[r * 3 + 2];
    const float rn = sqrtf(rx * rx + ry * ry + rz * rz);

    // ---- stable rank sort (u32 depth bits monotonic for depth in [0,1),
    // exact jnp.argsort stability via original-index tie-break) ----
    const unsigned b0 = __float_as_uint(d0);   // orig index lane
    const unsigned b1 = __float_as_uint(d1);   // orig index 64+lane
    int rank0 = 0, rank1 = 0;
    #pragma unroll 8
    for (int j = 0; j < 64; ++j) {
        const unsigned q0 = (unsigned)__shfl((int)b0, j);   // orig idx j
        const unsigned q1 = (unsigned)__shfl((int)b1, j);   // orig idx 64+j
        rank0 += (q0 < b0 || (q0 == b0 && j < lane)) ? 1 : 0;
        rank0 += (q1 < b0) ? 1 : 0;                  // 64+j > lane: tie loses
        rank1 += (q0 < b1 || q0 == b1) ? 1 : 0;      // j < 64+lane: tie wins
        rank1 += (q1 < b1 || (q1 == b1 && j < lane)) ? 1 : 0;
    }

    // ---- permute depth/sigma to sorted order via per-wave LDS ----
    sdep[rank0] = d0; sdep[rank1] = d1;
    ssig[rank0] = g0; ssig[rank1] = g1;
    WAVE_SYNC();
    const float sd_lo = sdep[lane];        // position lane
    const float sd_hi = sdep[64 + lane];   // position 64+lane
    const float sg_lo = ssig[lane];
    const float sg_hi = ssig[64 + lane];

    // ---- dists: d[q+1] - d[q]; last position gets 1e10 ----
    float dn_lo = __shfl_down(sd_lo, 1);
    const float sd_hi0 = __shfl(sd_hi, 0);
    if (lane == 63) dn_lo = sd_hi0;
    const float dn_hi = __shfl_down(sd_hi, 1);
    const float dz_lo = dn_lo - sd_lo;
    const float dz_hi = (lane == 63) ? 1e10f : (dn_hi - sd_hi);

    // ---- alpha, tp (match ref expression order) ----
    const float a_lo  = 1.0f - expf(-fmaxf(sg_lo, 0.0f) * dz_lo * rn);
    const float a_hi  = 1.0f - expf(-fmaxf(sg_hi, 0.0f) * dz_hi * rn);
    const float tp_lo = (1.0f - a_lo) + 1e-10f;
    const float tp_hi = (1.0f - a_hi) + 1e-10f;

    // ---- inclusive product scan over 128 positions (lo scan, hi scan, glue) --
    float sc_lo = tp_lo, sc_hi = tp_hi;
    #pragma unroll
    for (int off = 1; off < 64; off <<= 1) {
        const float vl = __shfl_up(sc_lo, off);
        const float vh = __shfl_up(sc_hi, off);
        if (lane >= off) { sc_lo *= vl; sc_hi *= vh; }
    }
    const float tot_lo = __shfl(sc_lo, 63);
    // exclusive transmittance
    float tr_lo = __shfl_up(sc_lo, 1);
    float tr_hi = __shfl_up(sc_hi, 1);
    if (lane == 0) { tr_lo = 1.0f; tr_hi = 1.0f; }
    tr_hi *= tot_lo;
    const float w_lo = a_lo * tr_lo;
    const float w_hi = a_hi * tr_hi;

    // ---- outputs: weights (sorted order), depth_map, alpha_map ----
    out_weights[(size_t)r * P + lane]      = w_lo;
    out_weights[(size_t)r * P + 64 + lane] = w_hi;

    float s1 = w_lo + w_hi;                    // w >= 0 so |w| = w
    float s2 = w_lo * sd_lo + w_hi * sd_hi;
    #pragma unroll
    for (int off = 32; off > 0; off >>= 1) {
        s1 += __shfl_xor(s1, off);
        s2 += __shfl_xor(s2, off);
    }
    if (lane == 0) {
        float dm = s2 / fmaxf(s1, 1e-12f);
        dm = (dm - 0.001f) / (1000.0f - 0.001f);
        dm = fminf(fmaxf(dm, 0.0f), 1.0f);
        out_depth[r] = dm;
        out_alpha[r] = s1;
    }

    // ---- w back to ORIGINAL sample order (pull from rank position) ----
    const float wa0 = __shfl(w_lo, rank0 & 63);
    const float wb0 = __shfl(w_hi, rank0 & 63);
    const float wo0 = (rank0 < 64) ? wa0 : wb0;   // orig sample lane
    const float wa1 = __shfl(w_lo, rank1 & 63);
    const float wb1 = __shfl(w_hi, rank1 & 63);
    const float wo1 = (rank1 < 64) ? wa1 : wb1;   // orig sample 64+lane

    // ---- nonzero compaction (ascending original p) into per-wave LDS ----
    const unsigned long long m0 = __ballot(wo0 != 0.0f);
    const unsigned long long m1 = __ballot(wo1 != 0.0f);
    const int M = (int)(__popcll(m0) + __popcll(m1));
    // bits strictly below `lane`; (1ull << lane) - 1 is well-defined for lane<=63
    const unsigned long long lmask = (1ull << lane) - 1ull;
    if (wo0 != 0.0f) {
        const int pos = (int)__popcll(m0 & lmask);
        plist[pos] = lane; swc[pos] = wo0;
    }
    if (wo1 != 0.0f) {
        const int pos = (int)__popcll(m0) + (int)__popcll(m1 & lmask);
        plist[pos] = 64 + lane; swc[pos] = wo1;
    }
    WAVE_SYNC();

    // ---- feat gather: chunks of 8 independent 1 KB loads (32 rows/chunk) ----
    const int f4   = lane & 15;   // float4 chunk of F
    const int psub = lane >> 4;   // 0..3
    const float4* fp = (const float4*)(feat + (size_t)r * P * F);
    const int jcap = (M > 0) ? (M - 1) : 0;
    const int nch  = (M + 31) >> 5;

    float4 acc = make_float4(0.f, 0.f, 0.f, 0.f);
    for (int c = 0; c < nch; ++c) {
        const int base = c * 32;
        int   pj[8];
        float wj[8];
        #pragma unroll
        for (int i = 0; i < 8; ++i) {
            const int idx = base + i * 4 + psub;
            const int j   = (idx < M) ? idx : jcap;
            pj[i] = plist[j] & (P - 1);
            wj[i] = (idx < M) ? swc[j] : 0.0f;
        }
        float4 fv[8];
        #pragma unroll
        for (int i = 0; i < 8; ++i)
            fv[i] = fp[pj[i] * (F / 4) + f4];
        #pragma unroll
        for (int i = 0; i < 8; ++i) {
            acc.x += wj[i] * fv[i].x;
            acc.y += wj[i] * fv[i].y;
            acc.z += wj[i] * fv[i].z;
            acc.w += wj[i] * fv[i].w;
        }
    }

    // reduce over psub (lane bits 4,5)
    acc.x += __shfl_xor(acc.x, 16); acc.y += __shfl_xor(acc.y, 16);
    acc.z += __shfl_xor(acc.z, 16); acc.w += __shfl_xor(acc.w, 16);
    acc.x += __shfl_xor(acc.x, 32); acc.y += __shfl_xor(acc.y, 32);
    acc.z += __shfl_xor(acc.z, 32); acc.w += __shfl_xor(acc.w, 32);

    if (psub == 0) {
        const int f = f4 * 4;
        out_feat[(size_t)(f + 0) * HW + r] = acc.x;
        out_feat[(size_t)(f + 1) * HW + r] = acc.y;
        out_feat[(size_t)(f + 2) * HW + r] = acc.z;
        out_feat[(size_t)(f + 3) * HW + r] = acc.w;
    }
}

extern "C" void kernel_launch(void* const* d_in, const int* in_sizes, int n_in,
                              void* d_out, int out_size, void* d_ws, size_t ws_size,
                              hipStream_t stream) {
    const float* sigma    = (const float*)d_in[0];
    const float* feat     = (const float*)d_in[1];
    const float* depth    = (const float*)d_in[2];
    // d_in[3] = semantic: sorted in the reference but unused in every output.
    const float* rays_dir = (const float*)d_in[4];

    float* out = (float*)d_out;
    // Flat output layout (return order): feat_map[64*16384], depth_map[16384],
    // alpha_map[16384], weights[16384*128]
    float* out_feat    = out;
    float* out_depth   = out + (size_t)F * HW;
    float* out_alpha   = out_depth + HW;
    float* out_weights = out_alpha + HW;

    nerf_wave_kernel<<<HW / 4, 256, 0, stream>>>(sigma, feat, depth, rays_dir,
                                                 out_feat, out_depth, out_alpha,
                                                 out_weights);
}